// Round 1
// baseline (327.066 us; speedup 1.0000x reference)
//
#include <hip/hip_runtime.h>

#define D_FEAT 128

// Kernel 1: zero output accumulator and degree array.
__global__ void zero_kernel(float* __restrict__ out, float* __restrict__ deg,
                            int n_out, int n_deg) {
    int i = blockIdx.x * blockDim.x + threadIdx.x;
    if (i < n_out) out[i] = 0.0f;
    if (i < n_deg) deg[i] = 0.0f;
}

// Kernel 2: edge-parallel scatter-add. One thread per (edge, feature).
// 128 consecutive threads handle one edge -> coalesced row read + coalesced
// atomic adds into the destination row. Lane f==0 bumps in-degree.
__global__ void scatter_kernel(const float* __restrict__ feat,
                               const int* __restrict__ src,
                               const int* __restrict__ dst,
                               float* __restrict__ out,
                               float* __restrict__ deg,
                               int n_edges) {
    long long gid = (long long)blockIdx.x * blockDim.x + threadIdx.x;
    int e = (int)(gid >> 7);   // edge index
    int f = (int)(gid & 127);  // feature index
    if (e >= n_edges) return;
    int s = src[e];
    int d = dst[e];
    float v = feat[(long long)s * D_FEAT + f];
    atomicAdd(&out[(long long)d * D_FEAT + f], v);
    if (f == 0) atomicAdd(&deg[d], 1.0f);
}

// Kernel 3: scale each row by max(deg,1)^-0.5.
__global__ void norm_kernel(float* __restrict__ out, const float* __restrict__ deg,
                            int n_out) {
    int gid = blockIdx.x * blockDim.x + threadIdx.x;
    if (gid >= n_out) return;
    int i = gid >> 7;  // node index
    float dg = fmaxf(deg[i], 1.0f);
    out[gid] = out[gid] * rsqrtf(dg);
}

extern "C" void kernel_launch(void* const* d_in, const int* in_sizes, int n_in,
                              void* d_out, int out_size, void* d_ws, size_t ws_size,
                              hipStream_t stream) {
    const float* feat = (const float*)d_in[0];
    const int*   src  = (const int*)d_in[1];
    const int*   dst  = (const int*)d_in[2];
    float* out = (float*)d_out;
    float* deg = (float*)d_ws;  // n_nodes floats of scratch

    const int n_edges = in_sizes[1];
    const int n_out   = out_size;            // n_nodes * 128
    const int n_nodes = n_out / D_FEAT;

    {
        int threads = 256;
        int blocks  = (n_out + threads - 1) / threads;
        zero_kernel<<<blocks, threads, 0, stream>>>(out, deg, n_out, n_nodes);
    }
    {
        long long total = (long long)n_edges * D_FEAT;
        int threads = 256;
        int blocks  = (int)((total + threads - 1) / threads);
        scatter_kernel<<<blocks, threads, 0, stream>>>(feat, src, dst, out, deg, n_edges);
    }
    {
        int threads = 256;
        int blocks  = (n_out + threads - 1) / threads;
        norm_kernel<<<blocks, threads, 0, stream>>>(out, deg, n_out);
    }
}

// Round 2
// 145.008 us; speedup vs baseline: 2.2555x; 2.2555x over previous
//
#include <hip/hip_runtime.h>

#define D_FEAT 128
#define SCAN_BLOCK 1024

// ---------------- CSR-based path (no fp32 atomics) ----------------

__global__ void zero_counts_kernel(int* __restrict__ cnt, int n) {
    int i = blockIdx.x * blockDim.x + threadIdx.x;
    if (i < n) cnt[i] = 0;
}

__global__ void hist_kernel(const int* __restrict__ dst, int* __restrict__ cnt,
                            int n_edges) {
    int e = blockIdx.x * blockDim.x + threadIdx.x;
    if (e < n_edges) atomicAdd(&cnt[dst[e]], 1);
}

// Single-block exclusive scan over n counts -> off[0..n], cur[0..n-1].
__global__ void scan_kernel(const int* __restrict__ cnt, int* __restrict__ off,
                            int* __restrict__ cur, int n) {
    __shared__ int sdata[SCAN_BLOCK];
    int t = threadIdx.x;
    int chunk = (n + SCAN_BLOCK - 1) / SCAN_BLOCK;
    int base = t * chunk;
    int sum = 0;
    for (int j = 0; j < chunk; ++j) {
        int idx = base + j;
        if (idx < n) sum += cnt[idx];
    }
    sdata[t] = sum;
    __syncthreads();
    for (int s = 1; s < SCAN_BLOCK; s <<= 1) {
        int v = (t >= s) ? sdata[t - s] : 0;
        __syncthreads();
        sdata[t] += v;
        __syncthreads();
    }
    int running = sdata[t] - sum;  // exclusive prefix of this thread's chunk
    for (int j = 0; j < chunk; ++j) {
        int idx = base + j;
        if (idx < n) {
            int c = cnt[idx];
            off[idx] = running;
            cur[idx] = running;
            running += c;
        }
    }
    if (t == SCAN_BLOCK - 1) off[n] = sdata[t];
}

__global__ void fill_kernel(const int* __restrict__ src, const int* __restrict__ dst,
                            int* __restrict__ cur, int* __restrict__ csr_src,
                            int n_edges) {
    int e = blockIdx.x * blockDim.x + threadIdx.x;
    if (e >= n_edges) return;
    int pos = atomicAdd(&cur[dst[e]], 1);
    csr_src[pos] = src[e];
}

// One 64-lane wave per node; each lane owns a float2 (2 feature columns).
__global__ void gather_kernel(const float* __restrict__ feat,
                              const int* __restrict__ off,
                              const int* __restrict__ csr_src,
                              float* __restrict__ out, int n_nodes) {
    int gtid = blockIdx.x * blockDim.x + threadIdx.x;
    int node = gtid >> 6;
    int lane = gtid & 63;
    if (node >= n_nodes) return;
    int beg = off[node];
    int end = off[node + 1];
    const float2* f2 = (const float2*)feat;  // row stride 64 float2

    float2 a0 = {0.f, 0.f}, a1 = {0.f, 0.f}, a2 = {0.f, 0.f}, a3 = {0.f, 0.f};
    int i = beg;
    for (; i + 3 < end; i += 4) {
        int s0 = csr_src[i + 0];
        int s1 = csr_src[i + 1];
        int s2 = csr_src[i + 2];
        int s3 = csr_src[i + 3];
        float2 v0 = f2[(size_t)s0 * 64 + lane];
        float2 v1 = f2[(size_t)s1 * 64 + lane];
        float2 v2 = f2[(size_t)s2 * 64 + lane];
        float2 v3 = f2[(size_t)s3 * 64 + lane];
        a0.x += v0.x; a0.y += v0.y;
        a1.x += v1.x; a1.y += v1.y;
        a2.x += v2.x; a2.y += v2.y;
        a3.x += v3.x; a3.y += v3.y;
    }
    for (; i < end; ++i) {
        int s = csr_src[i];
        float2 v = f2[(size_t)s * 64 + lane];
        a0.x += v.x; a0.y += v.y;
    }
    float2 r;
    r.x = (a0.x + a1.x) + (a2.x + a3.x);
    r.y = (a0.y + a1.y) + (a2.y + a3.y);
    int deg = end - beg;
    float scale = rsqrtf((float)(deg > 1 ? deg : 1));
    r.x *= scale;
    r.y *= scale;
    ((float2*)out)[(size_t)node * 64 + lane] = r;
}

// ---------------- Fallback path (round-1, fp32 atomics) ----------------

__global__ void zero_kernel(float* __restrict__ out, float* __restrict__ deg,
                            int n_out, int n_deg) {
    int i = blockIdx.x * blockDim.x + threadIdx.x;
    if (i < n_out) out[i] = 0.0f;
    if (i < n_deg) deg[i] = 0.0f;
}

__global__ void scatter_kernel(const float* __restrict__ feat,
                               const int* __restrict__ src,
                               const int* __restrict__ dst,
                               float* __restrict__ out,
                               float* __restrict__ deg,
                               int n_edges) {
    long long gid = (long long)blockIdx.x * blockDim.x + threadIdx.x;
    int e = (int)(gid >> 7);
    int f = (int)(gid & 127);
    if (e >= n_edges) return;
    int s = src[e];
    int d = dst[e];
    float v = feat[(long long)s * D_FEAT + f];
    atomicAdd(&out[(long long)d * D_FEAT + f], v);
    if (f == 0) atomicAdd(&deg[d], 1.0f);
}

__global__ void norm_kernel(float* __restrict__ out, const float* __restrict__ deg,
                            int n_out) {
    int gid = blockIdx.x * blockDim.x + threadIdx.x;
    if (gid >= n_out) return;
    int i = gid >> 7;
    float dg = fmaxf(deg[i], 1.0f);
    out[gid] = out[gid] * rsqrtf(dg);
}

extern "C" void kernel_launch(void* const* d_in, const int* in_sizes, int n_in,
                              void* d_out, int out_size, void* d_ws, size_t ws_size,
                              hipStream_t stream) {
    const float* feat = (const float*)d_in[0];
    const int*   src  = (const int*)d_in[1];
    const int*   dst  = (const int*)d_in[2];
    float* out = (float*)d_out;

    const int n_edges = in_sizes[1];
    const int n_out   = out_size;          // n_nodes * 128
    const int n_nodes = n_out / D_FEAT;

    // Workspace layout: cnt[n_nodes] | cur[n_nodes] | off[n_nodes+1] | csr_src[n_edges]
    size_t need = (size_t)(n_nodes * 2 + (n_nodes + 1) + n_edges) * sizeof(int);
    if (ws_size >= need) {
        int* cnt = (int*)d_ws;
        int* cur = cnt + n_nodes;
        int* off = cur + n_nodes;
        int* csr = off + (n_nodes + 1);

        {
            int threads = 256;
            int blocks = (n_nodes + threads - 1) / threads;
            zero_counts_kernel<<<blocks, threads, 0, stream>>>(cnt, n_nodes);
        }
        {
            int threads = 256;
            int blocks = (n_edges + threads - 1) / threads;
            hist_kernel<<<blocks, threads, 0, stream>>>(dst, cnt, n_edges);
        }
        scan_kernel<<<1, SCAN_BLOCK, 0, stream>>>(cnt, off, cur, n_nodes);
        {
            int threads = 256;
            int blocks = (n_edges + threads - 1) / threads;
            fill_kernel<<<blocks, threads, 0, stream>>>(src, dst, cur, csr, n_edges);
        }
        {
            int threads = 256;                       // 4 nodes per block
            int blocks = (n_nodes * 64 + threads - 1) / threads;
            gather_kernel<<<blocks, threads, 0, stream>>>(feat, off, csr, out, n_nodes);
        }
    } else {
        float* deg = (float*)d_ws;
        {
            int threads = 256;
            int blocks = (n_out + threads - 1) / threads;
            zero_kernel<<<blocks, threads, 0, stream>>>(out, deg, n_out, n_nodes);
        }
        {
            long long total = (long long)n_edges * D_FEAT;
            int threads = 256;
            int blocks = (int)((total + threads - 1) / threads);
            scatter_kernel<<<blocks, threads, 0, stream>>>(feat, src, dst, out, deg, n_edges);
        }
        {
            int threads = 256;
            int blocks = (n_out + threads - 1) / threads;
            norm_kernel<<<blocks, threads, 0, stream>>>(out, deg, n_out);
        }
    }
}

// Round 3
// 80.746 us; speedup vs baseline: 4.0506x; 1.7959x over previous
//
#include <hip/hip_runtime.h>

#define D_FEAT 128
#define MAX_OVF 4096

// ---------------- fixed-capacity bucket CSR path ----------------

// Zero cnt[n_nodes] and ovf_cnt (stored at cnt[n_nodes]).
__global__ void init_kernel(int* __restrict__ cnt, int n) {
    int i = blockIdx.x * blockDim.x + threadIdx.x;
    if (i < n) cnt[i] = 0;
}

// One thread per edge: allocate a slot in the destination's bucket.
__global__ void fill_cap_kernel(const int* __restrict__ src,
                                const int* __restrict__ dst,
                                int* __restrict__ cnt,
                                int* __restrict__ ovf_cnt,
                                int* __restrict__ ovf,
                                int* __restrict__ csr,
                                int n_edges, int cap) {
    int e = blockIdx.x * blockDim.x + threadIdx.x;
    if (e >= n_edges) return;
    int s = src[e];
    int d = dst[e];
    int pos = atomicAdd(&cnt[d], 1);
    if (pos < cap) {
        csr[(long long)d * cap + pos] = s;
    } else {
        int o = atomicAdd(ovf_cnt, 1);
        if (o < MAX_OVF) { ovf[2 * o] = s; ovf[2 * o + 1] = d; }
    }
}

// One 64-lane wave per node. Each lane owns 2 feature columns (float2).
// Edge ids are loaded coalesced (one lane = one edge), then broadcast with
// v_readlane so the row address is scalar + lane offset.
__global__ void gather_cap_kernel(const float* __restrict__ feat,
                                  const int* __restrict__ cnt,
                                  const int* __restrict__ csr,
                                  float* __restrict__ out,
                                  int n_nodes, int cap) {
    int gtid = blockIdx.x * blockDim.x + threadIdx.x;
    int node = gtid >> 6;
    int lane = gtid & 63;
    if (node >= n_nodes) return;
    int full = cnt[node];
    int deg  = full < cap ? full : cap;
    const float2* f2 = (const float2*)feat;   // row = 64 float2
    const int* base = csr + (long long)node * cap;

    float2 a0 = {0.f, 0.f}, a1 = {0.f, 0.f}, a2 = {0.f, 0.f}, a3 = {0.f, 0.f};
    for (int chunk = 0; chunk < deg; chunk += 64) {
        int m = deg - chunk; if (m > 64) m = 64;
        int idx = chunk + lane; if (idx > deg - 1) idx = deg - 1;
        int eid = base[idx];   // coalesced: 64 edge ids in one load
        int j = 0;
        for (; j + 3 < m; j += 4) {
            int s0 = __builtin_amdgcn_readlane(eid, j + 0);
            int s1 = __builtin_amdgcn_readlane(eid, j + 1);
            int s2 = __builtin_amdgcn_readlane(eid, j + 2);
            int s3 = __builtin_amdgcn_readlane(eid, j + 3);
            float2 v0 = f2[(size_t)s0 * 64 + lane];
            float2 v1 = f2[(size_t)s1 * 64 + lane];
            float2 v2 = f2[(size_t)s2 * 64 + lane];
            float2 v3 = f2[(size_t)s3 * 64 + lane];
            a0.x += v0.x; a0.y += v0.y;
            a1.x += v1.x; a1.y += v1.y;
            a2.x += v2.x; a2.y += v2.y;
            a3.x += v3.x; a3.y += v3.y;
        }
        for (; j < m; ++j) {
            int s = __builtin_amdgcn_readlane(eid, j);
            float2 v = f2[(size_t)s * 64 + lane];
            a0.x += v.x; a0.y += v.y;
        }
    }
    float2 r;
    r.x = (a0.x + a1.x) + (a2.x + a3.x);
    r.y = (a0.y + a1.y) + (a2.y + a3.y);
    float dg = (float)(full > 1 ? full : 1);
    float sc = rsqrtf(dg);
    r.x *= sc; r.y *= sc;
    ((float2*)out)[(size_t)node * 64 + lane] = r;
}

// Handle bucket-overflow edges (expected count: 0). Adds normalized
// contributions on top of gather's output.
__global__ void patch_kernel(const float* __restrict__ feat,
                             const int* __restrict__ cnt,
                             const int* __restrict__ ovf_cnt,
                             const int* __restrict__ ovf,
                             float* __restrict__ out) {
    int novf = *ovf_cnt;
    if (novf > MAX_OVF) novf = MAX_OVF;
    long long total  = (long long)novf * D_FEAT;
    long long stride = (long long)gridDim.x * blockDim.x;
    for (long long i = (long long)blockIdx.x * blockDim.x + threadIdx.x;
         i < total; i += stride) {
        int o = (int)(i >> 7);
        int f = (int)(i & 127);
        int s = ovf[2 * o];
        int d = ovf[2 * o + 1];
        int dgi = cnt[d]; if (dgi < 1) dgi = 1;
        float v = feat[(long long)s * D_FEAT + f] * rsqrtf((float)dgi);
        atomicAdd(&out[(long long)d * D_FEAT + f], v);
    }
}

// ---------------- fallback path (fp32 atomics) ----------------

__global__ void zero_kernel(float* __restrict__ out, float* __restrict__ deg,
                            int n_out, int n_deg) {
    int i = blockIdx.x * blockDim.x + threadIdx.x;
    if (i < n_out) out[i] = 0.0f;
    if (i < n_deg) deg[i] = 0.0f;
}

__global__ void scatter_kernel(const float* __restrict__ feat,
                               const int* __restrict__ src,
                               const int* __restrict__ dst,
                               float* __restrict__ out,
                               float* __restrict__ deg,
                               int n_edges) {
    long long gid = (long long)blockIdx.x * blockDim.x + threadIdx.x;
    int e = (int)(gid >> 7);
    int f = (int)(gid & 127);
    if (e >= n_edges) return;
    int s = src[e];
    int d = dst[e];
    float v = feat[(long long)s * D_FEAT + f];
    atomicAdd(&out[(long long)d * D_FEAT + f], v);
    if (f == 0) atomicAdd(&deg[d], 1.0f);
}

__global__ void norm_kernel(float* __restrict__ out, const float* __restrict__ deg,
                            int n_out) {
    int gid = blockIdx.x * blockDim.x + threadIdx.x;
    if (gid >= n_out) return;
    int i = gid >> 7;
    float dg = fmaxf(deg[i], 1.0f);
    out[gid] = out[gid] * rsqrtf(dg);
}

extern "C" void kernel_launch(void* const* d_in, const int* in_sizes, int n_in,
                              void* d_out, int out_size, void* d_ws, size_t ws_size,
                              hipStream_t stream) {
    const float* feat = (const float*)d_in[0];
    const int*   src  = (const int*)d_in[1];
    const int*   dst  = (const int*)d_in[2];
    float* out = (float*)d_out;

    const int n_edges = in_sizes[1];
    const int n_out   = out_size;           // n_nodes * 128
    const int n_nodes = n_out / D_FEAT;

    // ws layout: cnt[n_nodes] | ovf_cnt[1] | pad[1] | ovf[2*MAX_OVF] | csr[n_nodes*cap]
    auto need = [&](int cap) -> size_t {
        return (size_t)(n_nodes + 2 + 2 * MAX_OVF + (size_t)n_nodes * cap) * sizeof(int);
    };
    int cap = 0;
    if (ws_size >= need(128))      cap = 128;
    else if (ws_size >= need(96))  cap = 96;

    if (cap > 0) {
        int* cnt     = (int*)d_ws;
        int* ovf_cnt = cnt + n_nodes;
        int* ovf     = cnt + n_nodes + 2;
        int* csr     = ovf + 2 * MAX_OVF;

        {
            int threads = 256;
            int blocks = (n_nodes + 1 + threads - 1) / threads;
            init_kernel<<<blocks, threads, 0, stream>>>(cnt, n_nodes + 1);
        }
        {
            int threads = 256;
            int blocks = (n_edges + threads - 1) / threads;
            fill_cap_kernel<<<blocks, threads, 0, stream>>>(src, dst, cnt, ovf_cnt,
                                                            ovf, csr, n_edges, cap);
        }
        {
            int threads = 256;  // 4 waves/block, 1 wave per node
            int blocks = (n_nodes * 64 + threads - 1) / threads;
            gather_cap_kernel<<<blocks, threads, 0, stream>>>(feat, cnt, csr, out,
                                                              n_nodes, cap);
        }
        patch_kernel<<<32, 256, 0, stream>>>(feat, cnt, ovf_cnt, ovf, out);
    } else {
        float* deg = (float*)d_ws;
        {
            int threads = 256;
            int blocks = (n_out + threads - 1) / threads;
            zero_kernel<<<blocks, threads, 0, stream>>>(out, deg, n_out, n_nodes);
        }
        {
            long long total = (long long)n_edges * D_FEAT;
            int threads = 256;
            int blocks = (int)((total + threads - 1) / threads);
            scatter_kernel<<<blocks, threads, 0, stream>>>(feat, src, dst, out, deg, n_edges);
        }
        {
            int threads = 256;
            int blocks = (n_out + threads - 1) / threads;
            norm_kernel<<<blocks, threads, 0, stream>>>(out, deg, n_out);
        }
    }
}